// Round 1
// baseline (202.766 us; speedup 1.0000x reference)
//
#include <hip/hip_runtime.h>

// Grouped_Soft_GSL_Block_PE fused kernel for MI355X (gfx950).
// B=8, IC2=128, N=2048, K=32, C=64, G=8, CPG=8, hidden=16.
// One block = one (b, 4 n-points) tile = 128 spatial cols, 256 threads / 4 waves.
// Wave w owns cols [32w, 32w+32) == one n -> softmax/reductions wave-local.

typedef __attribute__((ext_vector_type(8))) short bf16x8;
typedef __attribute__((ext_vector_type(4))) float f32x4;

#define EPS_BN 1e-5f

__device__ __forceinline__ unsigned pk2(float a, float b){
  // pack two f32 -> two bf16 (round-half-up) in one dword; low short = a
  unsigned ua = __float_as_uint(a) + 0x8000u;
  unsigned ub = __float_as_uint(b) + 0x8000u;
  return __builtin_amdgcn_perm(ub, ua, 0x07060302);
}
__device__ __forceinline__ short f2bf(float a){
  unsigned u = __float_as_uint(a);
  u += 0x7FFFu + ((u >> 16) & 1u);   // RNE
  return (short)(u >> 16);
}
__device__ __forceinline__ bf16x8 mk8(float4 a, float4 b){
  union { bf16x8 v; unsigned u[4]; } t;
  t.u[0] = pk2(a.x, a.y); t.u[1] = pk2(a.z, a.w);
  t.u[2] = pk2(b.x, b.y); t.u[3] = pk2(b.z, b.w);
  return t.v;
}
__device__ __forceinline__ float lrelu(float v){ return fmaxf(v, 0.2f*v); }

#define MFMA16(a,b,c) __builtin_amdgcn_mfma_f32_16x16x32_bf16((a),(b),(c),0,0,0)

__global__ __launch_bounds__(256, 2)
void gsl_fused(const float* __restrict__ x,       const float* __restrict__ rel_pos,
               const float* __restrict__ pos_w1,  const float* __restrict__ pos_g,
               const float* __restrict__ pos_bb,  const float* __restrict__ pos_m,
               const float* __restrict__ pos_v,   const float* __restrict__ pos_w2,
               const float* __restrict__ pos_b2,  const float* __restrict__ pe_w,
               const float* __restrict__ pe_b,    const float* __restrict__ trans_w,
               const float* __restrict__ tr_g,    const float* __restrict__ tr_bb,
               const float* __restrict__ tr_m,    const float* __restrict__ tr_v,
               const float* __restrict__ gate_w1, const float* __restrict__ ga_g,
               const float* __restrict__ ga_bb,   const float* __restrict__ ga_m,
               const float* __restrict__ ga_v,    const float* __restrict__ gate_w2,
               const float* __restrict__ gate_b2, const float* __restrict__ attn_w1,
               const float* __restrict__ at_g,    const float* __restrict__ at_bb,
               const float* __restrict__ at_m,    const float* __restrict__ at_v,
               const float* __restrict__ attn_w2, const float* __restrict__ attn_b2,
               float* __restrict__ out)
{
  // ---- LDS map (64768 B total) ----
  // [0,34816)      xbuf  [128 cols][136] bf16   (dead after main GEMM)
  //   aliased after barrier2: posbuf [128][72] @0 ; gabuf [128][40] @18432
  // [34816,45056)  relbuf [128][40] bf16        (outbuf [64][4] f32 aliases @34816, used after barrier2)
  // [45056,63488)  h1buf  [128][72] bf16
  // [63488,64768)  BN fold tables (320 f32)
  __shared__ __align__(16) char smem[64768];
  short* xbuf   = (short*)smem;
  short* posbuf = (short*)smem;
  short* gabuf  = (short*)(smem + 18432);
  short* relbuf = (short*)(smem + 34816);
  short* h1buf  = (short*)(smem + 45056);
  float* outbuf = (float*)(smem + 34816);
  float* tabs   = (float*)(smem + 63488);
  float* trS = tabs;       float* trB = tabs + 64;
  float* p1S = tabs + 128; float* p1B = tabs + 192;
  float* gaS = tabs + 256; float* gaB = tabs + 272;
  float* atS = tabs + 288; float* atB = tabs + 304;

  const int tid = threadIdx.x;
  const int wv  = tid >> 6;          // wave 0..3 (owns n = n0+wv)
  const int l   = tid & 63;
  const int l15 = l & 15, g4 = l >> 4;
  const int bidx = blockIdx.x;
  const int b  = bidx >> 9;          // 512 tiles per batch
  const int n0 = (bidx & 511) << 2;  // 4 n per tile
  const long sbase = (long)n0 * 32;  // spatial base of tile (per (b,chan) plane of 65536)

  // ---- init: BN folds + zero relbuf (K-padding must be 0) ----
  if (tid < 64){
    float s = tr_g[tid] * rsqrtf(tr_v[tid] + EPS_BN);
    trS[tid] = s; trB[tid] = tr_bb[tid] - tr_m[tid]*s;
    float s2 = pos_g[tid] * rsqrtf(pos_v[tid] + EPS_BN);
    p1S[tid] = s2; p1B[tid] = pos_bb[tid] - pos_m[tid]*s2;
  } else if (tid < 80){
    int c = tid - 64;
    float s = ga_g[c] * rsqrtf(ga_v[c] + EPS_BN);
    gaS[c] = s; gaB[c] = ga_bb[c] - ga_m[c]*s;
  } else if (tid < 96){
    int c = tid - 80;
    float s = at_g[c] * rsqrtf(at_v[c] + EPS_BN);
    atS[c] = s; atB[c] = at_bb[c] - at_m[c]*s;
  }
  {
    float4 z = make_float4(0.f,0.f,0.f,0.f);
    float4* rb = (float4*)relbuf;              // 10240 B = 640 float4
    for (int i = tid; i < 640; i += 256) rb[i] = z;
  }

  // ---- main-GEMM A fragments: rows 0..63 trans, 64..79 gate_h, 80..95 attn_h ----
  bf16x8 wfrag[6][4];
  {
    const float* base[6] = { trans_w, trans_w + 16*128, trans_w + 32*128,
                             trans_w + 48*128, gate_w1, attn_w1 };
    #pragma unroll
    for (int m = 0; m < 6; ++m){
      const float* rp = base[m] + l15*128 + 8*g4;
      #pragma unroll
      for (int ks = 0; ks < 4; ++ks){
        float4 a = *(const float4*)(rp + 32*ks);
        float4 b2 = *(const float4*)(rp + 32*ks + 4);
        wfrag[m][ks] = mk8(a, b2);
      }
    }
  }
  __syncthreads();   // barrier 1: tables + relbuf zeroing visible

  // ---- stage rel_pos -> relbuf (wave-local cols), chans 0..2 ----
  if (l < 32){
    int col = 32*wv + l;
    long sg = sbase + col;
    #pragma unroll
    for (int ch = 0; ch < 3; ++ch)
      relbuf[col*40 + ch] = f2bf(rel_pos[(((long)(b*3 + ch)) << 16) + sg]);
  }

  // ---- stage x -> xbuf bf16 [col][136], 4x4 register transpose, wave-local cols ----
  {
    const int q = l & 7, d8 = l >> 3;
    const int colb = 32*wv + 4*q;
    #pragma unroll
    for (int ps = 0; ps < 4; ++ps){
      const int cb = 32*ps + 4*d8;
      const float* xp = x + (((long)(b*128 + cb)) << 16) + sbase + colb;
      float4 f0 = *(const float4*)(xp);
      float4 f1 = *(const float4*)(xp + 65536);
      float4 f2 = *(const float4*)(xp + 2*65536);
      float4 f3 = *(const float4*)(xp + 3*65536);
      *(uint2*)(xbuf + (colb+0)*136 + cb) = make_uint2(pk2(f0.x,f1.x), pk2(f2.x,f3.x));
      *(uint2*)(xbuf + (colb+1)*136 + cb) = make_uint2(pk2(f0.y,f1.y), pk2(f2.y,f3.y));
      *(uint2*)(xbuf + (colb+2)*136 + cb) = make_uint2(pk2(f0.z,f1.z), pk2(f2.z,f3.z));
      *(uint2*)(xbuf + (colb+3)*136 + cb) = make_uint2(pk2(f0.w,f1.w), pk2(f2.w,f3.w));
    }
  }

  // ---- main GEMM: [96x128] @ xtile[128x(wave's 32 cols)] ----
  f32x4 acc[6][2];
  #pragma unroll
  for (int m = 0; m < 6; ++m){
    f32x4 z = {0.f,0.f,0.f,0.f};
    acc[m][0] = z; acc[m][1] = z;
  }
  const int col0 = 32*wv + l15, col1 = col0 + 16;
  #pragma unroll
  for (int ks = 0; ks < 4; ++ks){
    bf16x8 b0 = *(const bf16x8*)(xbuf + col0*136 + 32*ks + 8*g4);
    bf16x8 b1 = *(const bf16x8*)(xbuf + col1*136 + 32*ks + 8*g4);
    #pragma unroll
    for (int m = 0; m < 6; ++m){
      acc[m][0] = MFMA16(wfrag[m][ks], b0, acc[m][0]);
      acc[m][1] = MFMA16(wfrag[m][ks], b1, acc[m][1]);
    }
  }

  // ---- small A-fragments (loaded after main GEMM to bound VGPR pressure) ----
  bf16x8 pw1f[4];
  #pragma unroll
  for (int m2 = 0; m2 < 4; ++m2){
    bf16x8 t = {0,0,0,0,0,0,0,0};
    if (g4 == 0){
      const float* rp = pos_w1 + (16*m2 + l15)*3;
      t[0] = f2bf(rp[0]); t[1] = f2bf(rp[1]); t[2] = f2bf(rp[2]);
    }
    pw1f[m2] = t;
  }
  bf16x8 pw2f[4][2];
  #pragma unroll
  for (int m2 = 0; m2 < 4; ++m2){
    const float* rp = pos_w2 + (16*m2 + l15)*64 + 8*g4;
    #pragma unroll
    for (int ks = 0; ks < 2; ++ks){
      float4 a = *(const float4*)(rp + 32*ks);
      float4 b2 = *(const float4*)(rp + 32*ks + 4);
      pw2f[m2][ks] = mk8(a, b2);
    }
  }
  bf16x8 pef[2];
  #pragma unroll
  for (int ks = 0; ks < 2; ++ks){
    bf16x8 t = {0,0,0,0,0,0,0,0};
    if (l15 < 8){
      const float* rp = pe_w + l15*64 + 32*ks + 8*g4;
      t = mk8(*(const float4*)rp, *(const float4*)(rp + 4));
    }
    pef[ks] = t;
  }
  bf16x8 gaf;
  {
    bf16x8 t = {0,0,0,0,0,0,0,0};
    #pragma unroll
    for (int j = 0; j < 8; ++j){
      int k = 8*g4 + j;
      float v2 = 0.f;
      if (l15 < 8)       { if (k >= 16) v2 = attn_w2[l15*16 + (k-16)]; }
      else if (l15 == 8) { if (k < 16)  v2 = gate_w2[k]; }
      t[j] = f2bf(v2);
    }
    gaf = t;
  }

  // ---- pos layer 1: [64x3(pad32)] @ rel -> BN+lrelu -> h1buf ----
  {
    bf16x8 r0 = *(const bf16x8*)(relbuf + col0*40 + 8*g4);
    bf16x8 r1 = *(const bf16x8*)(relbuf + col1*40 + 8*g4);
    #pragma unroll
    for (int m2 = 0; m2 < 4; ++m2){
      int cb2 = 16*m2 + 4*g4;
      f32x4 z = {0.f,0.f,0.f,0.f};
      f32x4 d0 = MFMA16(pw1f[m2], r0, z);
      f32x4 d1 = MFMA16(pw1f[m2], r1, z);
      float s0 = p1S[cb2+0], s1 = p1S[cb2+1], s2 = p1S[cb2+2], s3 = p1S[cb2+3];
      float c0 = p1B[cb2+0], c1 = p1B[cb2+1], c2 = p1B[cb2+2], c3 = p1B[cb2+3];
      float h0 = lrelu(s0*d0[0]+c0), h1v = lrelu(s1*d0[1]+c1);
      float h2 = lrelu(s2*d0[2]+c2), h3 = lrelu(s3*d0[3]+c3);
      *(uint2*)(h1buf + col0*72 + cb2) = make_uint2(pk2(h0,h1v), pk2(h2,h3));
      h0 = lrelu(s0*d1[0]+c0); h1v = lrelu(s1*d1[1]+c1);
      h2 = lrelu(s2*d1[2]+c2); h3 = lrelu(s3*d1[3]+c3);
      *(uint2*)(h1buf + col1*72 + cb2) = make_uint2(pk2(h0,h1v), pk2(h2,h3));
    }
  }

  // ---- pos layer 2: pos_enc = pos_w2 @ h1 + pos_b2 ----
  f32x4 pacc[4][2];
  #pragma unroll
  for (int m2 = 0; m2 < 4; ++m2){
    f32x4 z = {0.f,0.f,0.f,0.f};
    pacc[m2][0] = z; pacc[m2][1] = z;
  }
  #pragma unroll
  for (int ks = 0; ks < 2; ++ks){
    bf16x8 h0 = *(const bf16x8*)(h1buf + col0*72 + 32*ks + 8*g4);
    bf16x8 h1v = *(const bf16x8*)(h1buf + col1*72 + 32*ks + 8*g4);
    #pragma unroll
    for (int m2 = 0; m2 < 4; ++m2){
      pacc[m2][0] = MFMA16(pw2f[m2][ks], h0, pacc[m2][0]);
      pacc[m2][1] = MFMA16(pw2f[m2][ks], h1v, pacc[m2][1]);
    }
  }
  #pragma unroll
  for (int m2 = 0; m2 < 4; ++m2){
    #pragma unroll
    for (int r = 0; r < 4; ++r){
      float pb = pos_b2[16*m2 + 4*g4 + r];
      pacc[m2][0][r] += pb; pacc[m2][1][r] += pb;
    }
  }

  // ---- trans epilogue: trans_feat = lrelu(BN(conv)) + pos_enc (kept f32 in acc[0..3]) ----
  #pragma unroll
  for (int m = 0; m < 4; ++m){
    #pragma unroll
    for (int r = 0; r < 4; ++r){
      int c = 16*m + 4*g4 + r;
      float s = trS[c], bb2 = trB[c];
      acc[m][0][r] = lrelu(s*acc[m][0][r] + bb2) + pacc[m][0][r];
      acc[m][1][r] = lrelu(s*acc[m][1][r] + bb2) + pacc[m][1][r];
    }
  }

  __syncthreads();  // barrier 2: all waves done with xbuf -> aliased posbuf/gabuf safe

  // ---- hidden epilogues -> gabuf: chans 0..15 gate_h, 16..31 attn_h ----
  {
    int hc = 4*g4;
    float gs0 = gaS[hc+0], gs1 = gaS[hc+1], gs2 = gaS[hc+2], gs3 = gaS[hc+3];
    float gc0 = gaB[hc+0], gc1 = gaB[hc+1], gc2 = gaB[hc+2], gc3 = gaB[hc+3];
    float as0 = atS[hc+0], as1 = atS[hc+1], as2 = atS[hc+2], as3 = atS[hc+3];
    float ac0 = atB[hc+0], ac1 = atB[hc+1], ac2 = atB[hc+2], ac3 = atB[hc+3];
    #pragma unroll
    for (int ct = 0; ct < 2; ++ct){
      int col = (ct == 0) ? col0 : col1;
      float q0 = lrelu(gs0*acc[4][ct][0] + gc0), q1 = lrelu(gs1*acc[4][ct][1] + gc1);
      float q2 = lrelu(gs2*acc[4][ct][2] + gc2), q3 = lrelu(gs3*acc[4][ct][3] + gc3);
      *(uint2*)(gabuf + col*40 + hc) = make_uint2(pk2(q0,q1), pk2(q2,q3));
      float a0 = lrelu(as0*acc[5][ct][0] + ac0), a1 = lrelu(as1*acc[5][ct][1] + ac1);
      float a2 = lrelu(as2*acc[5][ct][2] + ac2), a3 = lrelu(as3*acc[5][ct][3] + ac3);
      *(uint2*)(gabuf + col*40 + 16 + hc) = make_uint2(pk2(a0,a1), pk2(a2,a3));
    }
  }
  // ---- pos_enc -> posbuf (bf16) for pe_proj ----
  #pragma unroll
  for (int m2 = 0; m2 < 4; ++m2){
    int cb2 = 16*m2 + 4*g4;
    *(uint2*)(posbuf + col0*72 + cb2) =
      make_uint2(pk2(pacc[m2][0][0],pacc[m2][0][1]), pk2(pacc[m2][0][2],pacc[m2][0][3]));
    *(uint2*)(posbuf + col1*72 + cb2) =
      make_uint2(pk2(pacc[m2][1][0],pacc[m2][1][1]), pk2(pacc[m2][1][2],pacc[m2][1][3]));
  }

  // ---- pe_proj MFMA (rows 0..7) + gate/attn second-layer MFMA (rows 0..7 attn, row 8 gate) ----
  f32x4 peac0 = {0.f,0.f,0.f,0.f}, peac1 = peac0, gac0 = peac0, gac1 = peac0;
  #pragma unroll
  for (int ks = 0; ks < 2; ++ks){
    bf16x8 p0 = *(const bf16x8*)(posbuf + col0*72 + 32*ks + 8*g4);
    bf16x8 p1 = *(const bf16x8*)(posbuf + col1*72 + 32*ks + 8*g4);
    peac0 = MFMA16(pef[ks], p0, peac0);
    peac1 = MFMA16(pef[ks], p1, peac1);
  }
  {
    bf16x8 g0 = *(const bf16x8*)(gabuf + col0*40 + 8*g4);
    bf16x8 g1 = *(const bf16x8*)(gabuf + col1*40 + 8*g4);
    gac0 = MFMA16(gaf, g0, gac0);
    gac1 = MFMA16(gaf, g1, gac1);
  }

  // ---- epilogue: gate, logits, softmax over k (16 lanes x 2 coltiles), outputs ----
  float gv0 = __shfl(gac0[0], 32 + l15, 64);   // row 8 lives in lane group 2, reg 0
  float gv1 = __shfl(gac1[0], 32 + l15, 64);
  float gb2v = gate_b2[0];
  float gm0 = 1.f/(1.f + __expf(-(gv0 + gb2v)));
  float gm1 = 1.f/(1.f + __expf(-(gv1 + gb2v)));
  float lg0 = __logf(gm0 + 1e-6f), lg1 = __logf(gm1 + 1e-6f);

  float wg0[4], wg1[4];
  #pragma unroll
  for (int r = 0; r < 4; ++r){
    int row = 4*g4 + r;
    float ab = (row < 8) ? attn_b2[row] : 0.f;
    float pb = (row < 8) ? pe_b[row] : 0.f;
    float t0 = gac0[r] + peac0[r] + ab + pb + lg0;
    float t1 = gac1[r] + peac1[r] + ab + pb + lg1;
    float mx = fmaxf(t0, t1);
    #pragma unroll
    for (int d = 1; d < 16; d <<= 1) mx = fmaxf(mx, __shfl_xor(mx, d, 64));
    float e0 = __expf(t0 - mx), e1 = __expf(t1 - mx);
    float s = e0 + e1;
    #pragma unroll
    for (int d = 1; d < 16; d <<= 1) s += __shfl_xor(s, d, 64);
    float inv = 1.f / s;
    wg0[r] = e0 * inv; wg1[r] = e1 * inv;
  }
  // redistribute: every lane gets softmax weight for all 8 groups
  float wf0[8], wf1[8];
  #pragma unroll
  for (int gg = 0; gg < 8; ++gg){
    int src = 16*(gg >> 2) + l15;
    wf0[gg] = __shfl(wg0[gg & 3], src, 64);
    wf1[gg] = __shfl(wg1[gg & 3], src, 64);
  }
  const bool hi = (g4 >= 2);
  #pragma unroll
  for (int m = 0; m < 4; ++m){
    float w0 = hi ? wf0[2*m+1] : wf0[2*m];
    float w1 = hi ? wf1[2*m+1] : wf1[2*m];
    #pragma unroll
    for (int r = 0; r < 4; ++r){
      float sA = acc[m][0][r]*w0 + acc[m][1][r]*w1;
      float sM = fmaxf(acc[m][0][r]*gm0, acc[m][1][r]*gm1);
      #pragma unroll
      for (int d = 1; d < 16; d <<= 1){
        sA += __shfl_xor(sA, d, 64);
        sM = fmaxf(sM, __shfl_xor(sM, d, 64));
      }
      if (l15 == 0) outbuf[(16*m + 4*g4 + r)*4 + wv] = sA + sM;
    }
  }

  __syncthreads();  // barrier 3
  if (tid < 64){
    float4 o = *(const float4*)(outbuf + tid*4);
    *(float4*)(out + (((long)(b*64 + tid)) << 11) + n0) = o;
  }
}

extern "C" void kernel_launch(void* const* d_in, const int* in_sizes, int n_in,
                              void* d_out, int out_size, void* d_ws, size_t ws_size,
                              hipStream_t stream){
  (void)in_sizes; (void)n_in; (void)out_size; (void)d_ws; (void)ws_size;
  gsl_fused<<<dim3(4096), dim3(256), 0, stream>>>(
    (const float*)d_in[0],  (const float*)d_in[1],  (const float*)d_in[2],
    (const float*)d_in[3],  (const float*)d_in[4],  (const float*)d_in[5],
    (const float*)d_in[6],  (const float*)d_in[7],  (const float*)d_in[8],
    (const float*)d_in[9],  (const float*)d_in[10], (const float*)d_in[11],
    (const float*)d_in[12], (const float*)d_in[13], (const float*)d_in[14],
    (const float*)d_in[15], (const float*)d_in[16], (const float*)d_in[17],
    (const float*)d_in[18], (const float*)d_in[19], (const float*)d_in[20],
    (const float*)d_in[21], (const float*)d_in[22], (const float*)d_in[23],
    (const float*)d_in[24], (const float*)d_in[25], (const float*)d_in[26],
    (const float*)d_in[27], (const float*)d_in[28], (const float*)d_in[29],
    (float*)d_out);
}

// Round 2
// 199.074 us; speedup vs baseline: 1.0185x; 1.0185x over previous
//
#include <hip/hip_runtime.h>

// Grouped_Soft_GSL_Block_PE fused kernel for MI355X (gfx950).
// B=8, IC2=128, N=2048, K=32, C=64, G=8, CPG=8, hidden=16.
// One block = (b, 4 n) tile = 128 spatial cols, 256 threads / 4 waves.
// Wave wv owns cols [32wv,32wv+32) == one n -> all reductions wave-local.
// LDS 36096 B -> 4 blocks/CU; per-wave scratch aliases the wave's own dead
// xbuf slice (wave-local, no barriers needed).

typedef __attribute__((ext_vector_type(8))) short bf16x8;
typedef __attribute__((ext_vector_type(4))) float f32x4;

#define EPS_BN 1e-5f

__device__ __forceinline__ unsigned pk2(float a, float b){
  // pack two f32 -> two bf16 (round-half-up); low short = a
  unsigned ua = __float_as_uint(a) + 0x8000u;
  unsigned ub = __float_as_uint(b) + 0x8000u;
  return __builtin_amdgcn_perm(ub, ua, 0x07060302);
}
__device__ __forceinline__ short f2bf(float a){
  unsigned u = __float_as_uint(a);
  u += 0x7FFFu + ((u >> 16) & 1u);
  return (short)(u >> 16);
}
__device__ __forceinline__ bf16x8 mk8(float4 a, float4 b){
  union { bf16x8 v; unsigned u[4]; } t;
  t.u[0] = pk2(a.x, a.y); t.u[1] = pk2(a.z, a.w);
  t.u[2] = pk2(b.x, b.y); t.u[3] = pk2(b.z, b.w);
  return t.v;
}
__device__ __forceinline__ float lrelu(float v){ return fmaxf(v, 0.2f*v); }

#define MFMA16(a,b,c) __builtin_amdgcn_mfma_f32_16x16x32_bf16((a),(b),(c),0,0,0)

__global__ __launch_bounds__(256, 4)
void gsl_fused(const float* __restrict__ x,       const float* __restrict__ rel_pos,
               const float* __restrict__ pos_w1,  const float* __restrict__ pos_g,
               const float* __restrict__ pos_bb,  const float* __restrict__ pos_m,
               const float* __restrict__ pos_v,   const float* __restrict__ pos_w2,
               const float* __restrict__ pos_b2,  const float* __restrict__ pe_w,
               const float* __restrict__ pe_b,    const float* __restrict__ trans_w,
               const float* __restrict__ tr_g,    const float* __restrict__ tr_bb,
               const float* __restrict__ tr_m,    const float* __restrict__ tr_v,
               const float* __restrict__ gate_w1, const float* __restrict__ ga_g,
               const float* __restrict__ ga_bb,   const float* __restrict__ ga_m,
               const float* __restrict__ ga_v,    const float* __restrict__ gate_w2,
               const float* __restrict__ gate_b2, const float* __restrict__ attn_w1,
               const float* __restrict__ at_g,    const float* __restrict__ at_bb,
               const float* __restrict__ at_m,    const float* __restrict__ at_v,
               const float* __restrict__ attn_w2, const float* __restrict__ attn_b2,
               float* __restrict__ out)
{
  // LDS: xbuf [128 cols][136] bf16 = 34816 B ; tabs 1280 B f32. Total 36096.
  // Per-wave slice = smem + wv*8704 (the wave's 32 xbuf cols), reused after
  // the wave's main GEMM as: h1/posbuf [32][72] @0, gabuf [32][40] @4608,
  // outw [64] f32 @7168.
  __shared__ __align__(16) char smem[36096];
  short* xbuf = (short*)smem;
  float* tabs = (float*)(smem + 34816);
  float* trS = tabs;       float* trB = tabs + 64;
  float* p1S = tabs + 128; float* p1B = tabs + 192;
  float* gaS = tabs + 256; float* gaB = tabs + 272;
  float* atS = tabs + 288; float* atB = tabs + 304;

  const int tid = threadIdx.x;
  const int wv  = tid >> 6;
  const int l   = tid & 63;
  const int l15 = l & 15, g4 = l >> 4;
  const int bidx = blockIdx.x;
  const int b  = bidx >> 9;
  const int n0 = (bidx & 511) << 2;
  const long sbase = (long)n0 * 32;

  char* slice = smem + wv*8704;
  short* h1b  = (short*)slice;            // [32 local cols][72]
  short* posb = (short*)slice;            // alias (h1 dead after pos2)
  short* gab  = (short*)(slice + 4608);   // [32][40]
  float* outw = (float*)(slice + 7168);   // [64]

  // ---- BN fold tables ----
  if (tid < 64){
    float s = tr_g[tid] * rsqrtf(tr_v[tid] + EPS_BN);
    trS[tid] = s; trB[tid] = tr_bb[tid] - tr_m[tid]*s;
    float s2 = pos_g[tid] * rsqrtf(pos_v[tid] + EPS_BN);
    p1S[tid] = s2; p1B[tid] = pos_bb[tid] - pos_m[tid]*s2;
  } else if (tid < 80){
    int c = tid - 64;
    float s = ga_g[c] * rsqrtf(ga_v[c] + EPS_BN);
    gaS[c] = s; gaB[c] = ga_bb[c] - ga_m[c]*s;
  } else if (tid < 96){
    int c = tid - 80;
    float s = at_g[c] * rsqrtf(at_v[c] + EPS_BN);
    atS[c] = s; atB[c] = at_bb[c] - at_m[c]*s;
  }

  // ---- stage x -> xbuf bf16 [col][136] (wave-local cols, 8x4 reg transpose) ----
  {
    const int q = l & 7, d = l >> 3;
    const int colb = 32*wv + 4*q;
    #pragma unroll
    for (int ps = 0; ps < 2; ++ps){
      const int ch0 = 64*ps + 8*d;
      const float* xp = x + (((long)(b*128 + ch0)) << 16) + sbase + colb;
      float4 f0 = *(const float4*)(xp);
      float4 f1 = *(const float4*)(xp + 65536);
      float4 f2 = *(const float4*)(xp + 2*65536);
      float4 f3 = *(const float4*)(xp + 3*65536);
      float4 f4 = *(const float4*)(xp + 4*65536);
      float4 f5 = *(const float4*)(xp + 5*65536);
      float4 f6 = *(const float4*)(xp + 6*65536);
      float4 f7 = *(const float4*)(xp + 7*65536);
      const float* F0 = (const float*)&f0; const float* F1 = (const float*)&f1;
      const float* F2 = (const float*)&f2; const float* F3 = (const float*)&f3;
      const float* F4 = (const float*)&f4; const float* F5 = (const float*)&f5;
      const float* F6 = (const float*)&f6; const float* F7 = (const float*)&f7;
      #pragma unroll
      for (int i = 0; i < 4; ++i){
        union { bf16x8 v; unsigned u[4]; } t;
        t.u[0] = pk2(F0[i], F1[i]);
        t.u[1] = pk2(F2[i], F3[i]);
        t.u[2] = pk2(F4[i], F5[i]);
        t.u[3] = pk2(F6[i], F7[i]);
        *(bf16x8*)(xbuf + (colb+i)*136 + ch0) = t.v;
      }
    }
  }

  // ---- main GEMM: [96x128] @ xtile; A-fragments built per-ks (bounds VGPRs) ----
  f32x4 acc[6][2];
  #pragma unroll
  for (int m = 0; m < 6; ++m){
    f32x4 z = {0.f,0.f,0.f,0.f};
    acc[m][0] = z; acc[m][1] = z;
  }
  const int col0 = 32*wv + l15, col1 = col0 + 16;
  const int lc0 = l15, lc1 = l15 + 16;
  {
    const float* base[6] = { trans_w, trans_w + 16*128, trans_w + 32*128,
                             trans_w + 48*128, gate_w1, attn_w1 };
    #pragma unroll
    for (int ks = 0; ks < 4; ++ks){
      bf16x8 b0 = *(const bf16x8*)(xbuf + col0*136 + 32*ks + 8*g4);
      bf16x8 b1 = *(const bf16x8*)(xbuf + col1*136 + 32*ks + 8*g4);
      #pragma unroll
      for (int m = 0; m < 6; ++m){
        const float* rp = base[m] + l15*128 + 32*ks + 8*g4;
        bf16x8 af = mk8(*(const float4*)rp, *(const float4*)(rp + 4));
        acc[m][0] = MFMA16(af, b0, acc[m][0]);
        acc[m][1] = MFMA16(af, b1, acc[m][1]);
      }
    }
  }

  __syncthreads();   // barrier 1: tabs visible (placed late for wave independence)

  // ---- pos layer 1: reg-built fragments (K padded 3->32 with zeros) ----
  {
    bf16x8 r0 = {0,0,0,0,0,0,0,0}, r1 = {0,0,0,0,0,0,0,0};
    if (g4 == 0){
      const long sg = sbase + col0;
      r0[0] = f2bf(rel_pos[(((long)(3*b+0)) << 16) + sg]);
      r0[1] = f2bf(rel_pos[(((long)(3*b+1)) << 16) + sg]);
      r0[2] = f2bf(rel_pos[(((long)(3*b+2)) << 16) + sg]);
      r1[0] = f2bf(rel_pos[(((long)(3*b+0)) << 16) + sg + 16]);
      r1[1] = f2bf(rel_pos[(((long)(3*b+1)) << 16) + sg + 16]);
      r1[2] = f2bf(rel_pos[(((long)(3*b+2)) << 16) + sg + 16]);
    }
    #pragma unroll
    for (int m2 = 0; m2 < 4; ++m2){
      bf16x8 aw = {0,0,0,0,0,0,0,0};
      if (g4 == 0){
        const float* rp = pos_w1 + (16*m2 + l15)*3;
        aw[0] = f2bf(rp[0]); aw[1] = f2bf(rp[1]); aw[2] = f2bf(rp[2]);
      }
      f32x4 z = {0.f,0.f,0.f,0.f};
      f32x4 d0 = MFMA16(aw, r0, z);
      f32x4 d1 = MFMA16(aw, r1, z);
      int cb2 = 16*m2 + 4*g4;
      float s0 = p1S[cb2+0], s1 = p1S[cb2+1], s2 = p1S[cb2+2], s3 = p1S[cb2+3];
      float c0 = p1B[cb2+0], c1 = p1B[cb2+1], c2 = p1B[cb2+2], c3 = p1B[cb2+3];
      float h0 = lrelu(s0*d0[0]+c0), h1v = lrelu(s1*d0[1]+c1);
      float h2 = lrelu(s2*d0[2]+c2), h3 = lrelu(s3*d0[3]+c3);
      *(uint2*)(h1b + lc0*72 + cb2) = make_uint2(pk2(h0,h1v), pk2(h2,h3));
      h0 = lrelu(s0*d1[0]+c0); h1v = lrelu(s1*d1[1]+c1);
      h2 = lrelu(s2*d1[2]+c2); h3 = lrelu(s3*d1[3]+c3);
      *(uint2*)(h1b + lc1*72 + cb2) = make_uint2(pk2(h0,h1v), pk2(h2,h3));
    }
  }

  // ---- pos layer 2: pos_enc = pos_w2 @ h1 + pos_b2 ----
  f32x4 pacc[4][2];
  #pragma unroll
  for (int m2 = 0; m2 < 4; ++m2){
    f32x4 z = {0.f,0.f,0.f,0.f};
    pacc[m2][0] = z; pacc[m2][1] = z;
  }
  #pragma unroll
  for (int ks = 0; ks < 2; ++ks){
    bf16x8 h0 = *(const bf16x8*)(h1b + lc0*72 + 32*ks + 8*g4);
    bf16x8 h1v = *(const bf16x8*)(h1b + lc1*72 + 32*ks + 8*g4);
    #pragma unroll
    for (int m2 = 0; m2 < 4; ++m2){
      const float* rp = pos_w2 + (16*m2 + l15)*64 + 32*ks + 8*g4;
      bf16x8 af = mk8(*(const float4*)rp, *(const float4*)(rp + 4));
      pacc[m2][0] = MFMA16(af, h0, pacc[m2][0]);
      pacc[m2][1] = MFMA16(af, h1v, pacc[m2][1]);
    }
  }
  #pragma unroll
  for (int m2 = 0; m2 < 4; ++m2){
    #pragma unroll
    for (int r = 0; r < 4; ++r){
      float pb = pos_b2[16*m2 + 4*g4 + r];
      pacc[m2][0][r] += pb; pacc[m2][1][r] += pb;
    }
  }

  // ---- trans epilogue: trans_feat = lrelu(BN(conv)) + pos_enc ----
  #pragma unroll
  for (int m = 0; m < 4; ++m){
    #pragma unroll
    for (int r = 0; r < 4; ++r){
      int c = 16*m + 4*g4 + r;
      float s = trS[c], bb2 = trB[c];
      acc[m][0][r] = lrelu(s*acc[m][0][r] + bb2) + pacc[m][0][r];
      acc[m][1][r] = lrelu(s*acc[m][1][r] + bb2) + pacc[m][1][r];
    }
  }

  // ---- hidden epilogues -> gab: chans 0..15 gate_h, 16..31 attn_h ----
  {
    int hc = 4*g4;
    float gs0 = gaS[hc+0], gs1 = gaS[hc+1], gs2 = gaS[hc+2], gs3 = gaS[hc+3];
    float gc0 = gaB[hc+0], gc1 = gaB[hc+1], gc2 = gaB[hc+2], gc3 = gaB[hc+3];
    float as0 = atS[hc+0], as1 = atS[hc+1], as2 = atS[hc+2], as3 = atS[hc+3];
    float ac0 = atB[hc+0], ac1 = atB[hc+1], ac2 = atB[hc+2], ac3 = atB[hc+3];
    #pragma unroll
    for (int ct = 0; ct < 2; ++ct){
      int lc = (ct == 0) ? lc0 : lc1;
      float q0 = lrelu(gs0*acc[4][ct][0] + gc0), q1 = lrelu(gs1*acc[4][ct][1] + gc1);
      float q2 = lrelu(gs2*acc[4][ct][2] + gc2), q3 = lrelu(gs3*acc[4][ct][3] + gc3);
      *(uint2*)(gab + lc*40 + hc) = make_uint2(pk2(q0,q1), pk2(q2,q3));
      float a0 = lrelu(as0*acc[5][ct][0] + ac0), a1 = lrelu(as1*acc[5][ct][1] + ac1);
      float a2 = lrelu(as2*acc[5][ct][2] + ac2), a3 = lrelu(as3*acc[5][ct][3] + ac3);
      *(uint2*)(gab + lc*40 + 16 + hc) = make_uint2(pk2(a0,a1), pk2(a2,a3));
    }
  }
  // ---- pos_enc -> posb (bf16) for pe_proj (overwrites dead h1) ----
  #pragma unroll
  for (int m2 = 0; m2 < 4; ++m2){
    int cb2 = 16*m2 + 4*g4;
    *(uint2*)(posb + lc0*72 + cb2) =
      make_uint2(pk2(pacc[m2][0][0],pacc[m2][0][1]), pk2(pacc[m2][0][2],pacc[m2][0][3]));
    *(uint2*)(posb + lc1*72 + cb2) =
      make_uint2(pk2(pacc[m2][1][0],pacc[m2][1][1]), pk2(pacc[m2][1][2],pacc[m2][1][3]));
  }

  // ---- pe_proj MFMA (rows 0..7) + gate/attn layer-2 MFMA (rows 0..7 attn, row 8 gate) ----
  f32x4 peac0 = {0.f,0.f,0.f,0.f}, peac1 = peac0, gac0 = peac0, gac1 = peac0;
  #pragma unroll
  for (int ks = 0; ks < 2; ++ks){
    bf16x8 pf = {0,0,0,0,0,0,0,0};
    if (l15 < 8){
      const float* rp = pe_w + l15*64 + 32*ks + 8*g4;
      pf = mk8(*(const float4*)rp, *(const float4*)(rp + 4));
    }
    bf16x8 p0 = *(const bf16x8*)(posb + lc0*72 + 32*ks + 8*g4);
    bf16x8 p1 = *(const bf16x8*)(posb + lc1*72 + 32*ks + 8*g4);
    peac0 = MFMA16(pf, p0, peac0);
    peac1 = MFMA16(pf, p1, peac1);
  }
  {
    bf16x8 gaf = {0,0,0,0,0,0,0,0};
    #pragma unroll
    for (int j = 0; j < 8; ++j){
      int k = 8*g4 + j;
      float v2 = 0.f;
      if (l15 < 8)       { if (k >= 16) v2 = attn_w2[l15*16 + (k-16)]; }
      else if (l15 == 8) { if (k < 16)  v2 = gate_w2[k]; }
      gaf[j] = f2bf(v2);
    }
    bf16x8 g0 = *(const bf16x8*)(gab + lc0*40 + 8*g4);
    bf16x8 g1 = *(const bf16x8*)(gab + lc1*40 + 8*g4);
    gac0 = MFMA16(gaf, g0, gac0);
    gac1 = MFMA16(gaf, g1, gac1);
  }

  // ---- epilogue: gate, logits, softmax over k, outputs ----
  float gv0 = __shfl(gac0[0], 32 + l15, 64);
  float gv1 = __shfl(gac1[0], 32 + l15, 64);
  float gb2v = gate_b2[0];
  float gm0 = 1.f/(1.f + __expf(-(gv0 + gb2v)));
  float gm1 = 1.f/(1.f + __expf(-(gv1 + gb2v)));
  float lg0 = __logf(gm0 + 1e-6f), lg1 = __logf(gm1 + 1e-6f);

  float wg0[4], wg1[4];
  #pragma unroll
  for (int r = 0; r < 4; ++r){
    int row = 4*g4 + r;
    float ab = (row < 8) ? attn_b2[row] : 0.f;
    float pb = (row < 8) ? pe_b[row] : 0.f;
    float t0 = gac0[r] + peac0[r] + ab + pb + lg0;
    float t1 = gac1[r] + peac1[r] + ab + pb + lg1;
    float mx = fmaxf(t0, t1);
    #pragma unroll
    for (int d = 1; d < 16; d <<= 1) mx = fmaxf(mx, __shfl_xor(mx, d, 64));
    float e0 = __expf(t0 - mx), e1 = __expf(t1 - mx);
    float s = e0 + e1;
    #pragma unroll
    for (int d = 1; d < 16; d <<= 1) s += __shfl_xor(s, d, 64);
    float inv = 1.f / s;
    wg0[r] = e0 * inv; wg1[r] = e1 * inv;
  }
  float wf0[8], wf1[8];
  #pragma unroll
  for (int gg = 0; gg < 8; ++gg){
    int src = 16*(gg >> 2) + l15;
    wf0[gg] = __shfl(wg0[gg & 3], src, 64);
    wf1[gg] = __shfl(wg1[gg & 3], src, 64);
  }
  const bool hi = (g4 >= 2);
  #pragma unroll
  for (int m = 0; m < 4; ++m){
    float w0 = hi ? wf0[2*m+1] : wf0[2*m];
    float w1 = hi ? wf1[2*m+1] : wf1[2*m];
    #pragma unroll
    for (int r = 0; r < 4; ++r){
      float sA = acc[m][0][r]*w0 + acc[m][1][r]*w1;
      float sM = fmaxf(acc[m][0][r]*gm0, acc[m][1][r]*gm1);
      #pragma unroll
      for (int d = 1; d < 16; d <<= 1){
        sA += __shfl_xor(sA, d, 64);
        sM = fmaxf(sM, __shfl_xor(sM, d, 64));
      }
      if (l15 == 0) outw[16*m + 4*g4 + r] = sA + sM;
    }
  }

  __syncthreads();  // barrier 2: all waves' outw slices visible
  if (tid < 64){
    const char* sb = smem + 7168;
    float4 o;
    o.x = *(const float*)(sb + 0*8704 + tid*4);
    o.y = *(const float*)(sb + 1*8704 + tid*4);
    o.z = *(const float*)(sb + 2*8704 + tid*4);
    o.w = *(const float*)(sb + 3*8704 + tid*4);
    *(float4*)(out + (((long)(b*64 + tid)) << 11) + n0) = o;
  }
}

extern "C" void kernel_launch(void* const* d_in, const int* in_sizes, int n_in,
                              void* d_out, int out_size, void* d_ws, size_t ws_size,
                              hipStream_t stream){
  (void)in_sizes; (void)n_in; (void)out_size; (void)d_ws; (void)ws_size;
  gsl_fused<<<dim3(4096), dim3(256), 0, stream>>>(
    (const float*)d_in[0],  (const float*)d_in[1],  (const float*)d_in[2],
    (const float*)d_in[3],  (const float*)d_in[4],  (const float*)d_in[5],
    (const float*)d_in[6],  (const float*)d_in[7],  (const float*)d_in[8],
    (const float*)d_in[9],  (const float*)d_in[10], (const float*)d_in[11],
    (const float*)d_in[12], (const float*)d_in[13], (const float*)d_in[14],
    (const float*)d_in[15], (const float*)d_in[16], (const float*)d_in[17],
    (const float*)d_in[18], (const float*)d_in[19], (const float*)d_in[20],
    (const float*)d_in[21], (const float*)d_in[22], (const float*)d_in[23],
    (const float*)d_in[24], (const float*)d_in[25], (const float*)d_in[26],
    (const float*)d_in[27], (const float*)d_in[28], (const float*)d_in[29],
    (float*)d_out);
}

// Round 3
// 145.663 us; speedup vs baseline: 1.3920x; 1.3667x over previous
//
#include <hip/hip_runtime.h>

// Grouped_Soft_GSL_Block_PE fused kernel for MI355X (gfx950).
// B=8, IC2=128, N=2048, K=32, C=64, G=8, CPG=8, hidden=16.
// R3: software-pipelined. 512 blocks (2/CU), 256 thr / 4 waves.
// Block owns 32 consecutive n; 8 iterations of (4 n)-tiles; wave wv owns
// n = nblk + 4*it + wv. No barriers in the loop (per-wave-private LDS slices);
// x loads for tile t+1 issued before GEMM of tile t (latency hidden under
// compute). Weights staged to LDS as bf16 once per block.

typedef __attribute__((ext_vector_type(8))) short bf16x8;
typedef __attribute__((ext_vector_type(4))) float f32x4;

#define EPS_BN 1e-5f

__device__ __forceinline__ unsigned pk2(float a, float b){
  unsigned ua = __float_as_uint(a) + 0x8000u;
  unsigned ub = __float_as_uint(b) + 0x8000u;
  return __builtin_amdgcn_perm(ub, ua, 0x07060302);
}
__device__ __forceinline__ short f2bf(float a){
  unsigned u = __float_as_uint(a);
  u += 0x7FFFu + ((u >> 16) & 1u);
  return (short)(u >> 16);
}
__device__ __forceinline__ bf16x8 mk8(float4 a, float4 b){
  union { bf16x8 v; unsigned u[4]; } t;
  t.u[0] = pk2(a.x, a.y); t.u[1] = pk2(a.z, a.w);
  t.u[2] = pk2(b.x, b.y); t.u[3] = pk2(b.z, b.w);
  return t.v;
}
__device__ __forceinline__ float lrelu(float v){ return fmaxf(v, 0.2f*v); }

#define MFMA16(a,b,c) __builtin_amdgcn_mfma_f32_16x16x32_bf16((a),(b),(c),0,0,0)

__device__ __forceinline__ void xload(f32x4 (&f)[2][8], const float* xp0){
  #pragma unroll
  for (int ps = 0; ps < 2; ++ps){
    const float* xp = xp0 + (((long)(64*ps)) << 16);
    #pragma unroll
    for (int j = 0; j < 8; ++j)
      f[ps][j] = *(const f32x4*)(xp + (((long)j) << 16));
  }
}

__global__ __launch_bounds__(256, 2)
void gsl_fused(const float* __restrict__ x,       const float* __restrict__ rel_pos,
               const float* __restrict__ pos_w1,  const float* __restrict__ pos_g,
               const float* __restrict__ pos_bb,  const float* __restrict__ pos_m,
               const float* __restrict__ pos_v,   const float* __restrict__ pos_w2,
               const float* __restrict__ pos_b2,  const float* __restrict__ pe_w,
               const float* __restrict__ pe_b,    const float* __restrict__ trans_w,
               const float* __restrict__ tr_g,    const float* __restrict__ tr_bb,
               const float* __restrict__ tr_m,    const float* __restrict__ tr_v,
               const float* __restrict__ gate_w1, const float* __restrict__ ga_g,
               const float* __restrict__ ga_bb,   const float* __restrict__ ga_m,
               const float* __restrict__ ga_v,    const float* __restrict__ gate_w2,
               const float* __restrict__ gate_b2, const float* __restrict__ attn_w1,
               const float* __restrict__ at_g,    const float* __restrict__ at_bb,
               const float* __restrict__ at_m,    const float* __restrict__ at_v,
               const float* __restrict__ attn_w2, const float* __restrict__ attn_b2,
               float* __restrict__ out)
{
  // LDS map (79616 B):
  // [0,34816)      xbuf [128 cols][136] bf16; wave slice = 8704 B at wv*8704,
  //                re-aliased per-iteration after GEMM: h1/posb [32][72] @0,
  //                gab [32][40] @4608 (all wave-private, no barriers)
  // [34816,60928)  wmain [96 rows][136] bf16 (trans 0..63, gate 64..79, attn 80..95)
  // [60928,70144)  wpos2 [64 rows][72] bf16
  // [70144,78336)  outacc [64 ch][32 n] f32
  // [78336,79616)  BN fold tables (320 f32)
  __shared__ __align__(16) char smem[79616];
  short* xbuf  = (short*)smem;
  short* wmain = (short*)(smem + 34816);
  short* wpos2 = (short*)(smem + 60928);
  float* outacc= (float*)(smem + 70144);
  float* tabs  = (float*)(smem + 78336);
  float* trS = tabs;       float* trB = tabs + 64;
  float* p1S = tabs + 128; float* p1B = tabs + 192;
  float* gaS = tabs + 256; float* gaB = tabs + 272;
  float* atS = tabs + 288; float* atB = tabs + 304;

  const int tid = threadIdx.x;
  const int wv  = tid >> 6;
  const int l   = tid & 63;
  const int l15 = l & 15, g4 = l >> 4;
  const int bid = blockIdx.x;
  const int b    = bid >> 6;           // 64 blocks per batch
  const int nblk = (bid & 63) << 5;    // 32 n per block

  // ---- stage weights -> LDS bf16 (once per block) ----
  if (tid < 192){
    int r = tid >> 1, c0 = (tid & 1) * 64;
    const float* src = (r < 64) ? (trans_w + r*128)
                     : (r < 80) ? (gate_w1 + (r-64)*128)
                                : (attn_w1 + (r-80)*128);
    src += c0;
    short* dst = wmain + r*136 + c0;
    #pragma unroll
    for (int j = 0; j < 8; ++j){
      float4 a = *(const float4*)(src + 8*j);
      float4 bq = *(const float4*)(src + 8*j + 4);
      *(bf16x8*)(dst + 8*j) = mk8(a, bq);
    }
  } else {
    int r = tid - 192;
    const float* src = pos_w2 + r*64;
    short* dst = wpos2 + r*72;
    #pragma unroll
    for (int j = 0; j < 8; ++j){
      float4 a = *(const float4*)(src + 8*j);
      float4 bq = *(const float4*)(src + 8*j + 4);
      *(bf16x8*)(dst + 8*j) = mk8(a, bq);
    }
  }
  // ---- BN fold tables ----
  if (tid < 64){
    float s = tr_g[tid] * rsqrtf(tr_v[tid] + EPS_BN);
    trS[tid] = s; trB[tid] = tr_bb[tid] - tr_m[tid]*s;
    float s2 = pos_g[tid] * rsqrtf(pos_v[tid] + EPS_BN);
    p1S[tid] = s2; p1B[tid] = pos_bb[tid] - pos_m[tid]*s2;
  } else if (tid < 80){
    int c = tid - 64;
    float s = ga_g[c] * rsqrtf(ga_v[c] + EPS_BN);
    gaS[c] = s; gaB[c] = ga_bb[c] - ga_m[c]*s;
  } else if (tid < 96){
    int c = tid - 80;
    float s = at_g[c] * rsqrtf(at_v[c] + EPS_BN);
    atS[c] = s; atB[c] = at_bb[c] - at_m[c]*s;
  }

  // ---- small weights -> registers (once per block) ----
  bf16x8 pw1f[4];
  #pragma unroll
  for (int m2 = 0; m2 < 4; ++m2){
    bf16x8 t = {0,0,0,0,0,0,0,0};
    if (g4 == 0){
      const float* rp = pos_w1 + (16*m2 + l15)*3;
      t[0] = f2bf(rp[0]); t[1] = f2bf(rp[1]); t[2] = f2bf(rp[2]);
    }
    pw1f[m2] = t;
  }
  bf16x8 pef[2];
  #pragma unroll
  for (int ks = 0; ks < 2; ++ks){
    bf16x8 t = {0,0,0,0,0,0,0,0};
    if (l15 < 8){
      const float* rp = pe_w + l15*64 + 32*ks + 8*g4;
      t = mk8(*(const float4*)rp, *(const float4*)(rp + 4));
    }
    pef[ks] = t;
  }
  bf16x8 gaf;
  {
    bf16x8 t = {0,0,0,0,0,0,0,0};
    #pragma unroll
    for (int j = 0; j < 8; ++j){
      int k = 8*g4 + j;
      float v2 = 0.f;
      if (l15 < 8)       { if (k >= 16) v2 = attn_w2[l15*16 + (k-16)]; }
      else if (l15 == 8) { if (k < 16)  v2 = gate_w2[k]; }
      t[j] = f2bf(v2);
    }
    gaf = t;
  }

  __syncthreads();   // single barrier: LDS weights + tables visible

  // ---- per-wave constants ----
  const int col0 = 32*wv + l15, col1 = col0 + 16;
  const int lq = l & 7, ld = l >> 3;
  const int colb = 32*wv + 4*lq;
  char*  slice = smem + wv*8704;
  short* h1b   = (short*)slice;            // [32 local cols][72]
  short* posb  = (short*)slice;            // alias (h1 dead after pos2)
  short* gab   = (short*)(slice + 4608);   // [32][40]
  const int lc0 = l15, lc1 = l15 + 16;
  const float* xp0 = x + (((long)(b*128 + 8*ld)) << 16) + colb;

  // ---- prologue: issue x loads for iteration 0 ----
  f32x4 f[2][8];
  xload(f, xp0 + (long)nblk*32);

  for (int it = 0; it < 8; ++it){
    const long sbase = (long)nblk*32 + 128*it;

    // (1) cvt + write staged tile -> own xbuf slice
    #pragma unroll
    for (int ps = 0; ps < 2; ++ps){
      const int ch0 = 64*ps + 8*ld;
      #pragma unroll
      for (int i2 = 0; i2 < 4; ++i2){
        union { bf16x8 v; unsigned u[4]; } t;
        t.u[0] = pk2(f[ps][0][i2], f[ps][1][i2]);
        t.u[1] = pk2(f[ps][2][i2], f[ps][3][i2]);
        t.u[2] = pk2(f[ps][4][i2], f[ps][5][i2]);
        t.u[3] = pk2(f[ps][6][i2], f[ps][7][i2]);
        *(bf16x8*)(xbuf + (colb+i2)*136 + ch0) = t.v;
      }
    }

    // (2) rel_pos loads for this iteration (g4==0 lanes)
    float r0c0=0.f,r0c1=0.f,r0c2=0.f,r1c0=0.f,r1c1=0.f,r1c2=0.f;
    if (g4 == 0){
      const long sg = sbase + col0;
      r0c0 = rel_pos[(((long)(3*b+0)) << 16) + sg];
      r0c1 = rel_pos[(((long)(3*b+1)) << 16) + sg];
      r0c2 = rel_pos[(((long)(3*b+2)) << 16) + sg];
      r1c0 = rel_pos[(((long)(3*b+0)) << 16) + sg + 16];
      r1c1 = rel_pos[(((long)(3*b+1)) << 16) + sg + 16];
      r1c2 = rel_pos[(((long)(3*b+2)) << 16) + sg + 16];
    }

    // (3) prefetch next tile (stays in flight across GEMM+epilogue)
    if (it < 7) xload(f, xp0 + sbase + 128);

    // (4) main GEMM: [96x128] @ xtile (A-frags from LDS wmain)
    f32x4 acc[6][2];
    #pragma unroll
    for (int m = 0; m < 6; ++m){
      f32x4 z = {0.f,0.f,0.f,0.f};
      acc[m][0] = z; acc[m][1] = z;
    }
    #pragma unroll
    for (int ks = 0; ks < 4; ++ks){
      bf16x8 b0 = *(const bf16x8*)(xbuf + col0*136 + 32*ks + 8*g4);
      bf16x8 b1 = *(const bf16x8*)(xbuf + col1*136 + 32*ks + 8*g4);
      #pragma unroll
      for (int m = 0; m < 6; ++m){
        bf16x8 af = *(const bf16x8*)(wmain + (16*m + l15)*136 + 32*ks + 8*g4);
        acc[m][0] = MFMA16(af, b0, acc[m][0]);
        acc[m][1] = MFMA16(af, b1, acc[m][1]);
      }
    }

    // (5) pos layer 1 (K padded 3->32 with zeros) -> h1b
    {
      bf16x8 rf0 = {0,0,0,0,0,0,0,0}, rf1 = {0,0,0,0,0,0,0,0};
      if (g4 == 0){
        rf0[0] = f2bf(r0c0); rf0[1] = f2bf(r0c1); rf0[2] = f2bf(r0c2);
        rf1[0] = f2bf(r1c0); rf1[1] = f2bf(r1c1); rf1[2] = f2bf(r1c2);
      }
      #pragma unroll
      for (int m2 = 0; m2 < 4; ++m2){
        f32x4 z = {0.f,0.f,0.f,0.f};
        f32x4 d0 = MFMA16(pw1f[m2], rf0, z);
        f32x4 d1 = MFMA16(pw1f[m2], rf1, z);
        int cb2 = 16*m2 + 4*g4;
        float s0 = p1S[cb2+0], s1 = p1S[cb2+1], s2 = p1S[cb2+2], s3 = p1S[cb2+3];
        float c0 = p1B[cb2+0], c1 = p1B[cb2+1], c2 = p1B[cb2+2], c3 = p1B[cb2+3];
        float h0 = lrelu(s0*d0[0]+c0), h1v = lrelu(s1*d0[1]+c1);
        float h2 = lrelu(s2*d0[2]+c2), h3 = lrelu(s3*d0[3]+c3);
        *(uint2*)(h1b + lc0*72 + cb2) = make_uint2(pk2(h0,h1v), pk2(h2,h3));
        h0 = lrelu(s0*d1[0]+c0); h1v = lrelu(s1*d1[1]+c1);
        h2 = lrelu(s2*d1[2]+c2); h3 = lrelu(s3*d1[3]+c3);
        *(uint2*)(h1b + lc1*72 + cb2) = make_uint2(pk2(h0,h1v), pk2(h2,h3));
      }
    }

    // (6) pos layer 2: pos_enc = pos_w2 @ h1 + pos_b2 (A-frags from LDS wpos2)
    f32x4 pacc[4][2];
    #pragma unroll
    for (int m2 = 0; m2 < 4; ++m2){
      f32x4 z = {0.f,0.f,0.f,0.f};
      pacc[m2][0] = z; pacc[m2][1] = z;
    }
    #pragma unroll
    for (int ks = 0; ks < 2; ++ks){
      bf16x8 h0 = *(const bf16x8*)(h1b + lc0*72 + 32*ks + 8*g4);
      bf16x8 h1v = *(const bf16x8*)(h1b + lc1*72 + 32*ks + 8*g4);
      #pragma unroll
      for (int m2 = 0; m2 < 4; ++m2){
        bf16x8 af = *(const bf16x8*)(wpos2 + (16*m2 + l15)*72 + 32*ks + 8*g4);
        pacc[m2][0] = MFMA16(af, h0, pacc[m2][0]);
        pacc[m2][1] = MFMA16(af, h1v, pacc[m2][1]);
      }
    }
    #pragma unroll
    for (int m2 = 0; m2 < 4; ++m2){
      #pragma unroll
      for (int r = 0; r < 4; ++r){
        float pb = pos_b2[16*m2 + 4*g4 + r];
        pacc[m2][0][r] += pb; pacc[m2][1][r] += pb;
      }
    }

    // (7) trans epilogue: trans_feat = lrelu(BN(conv)) + pos_enc
    #pragma unroll
    for (int m = 0; m < 4; ++m){
      #pragma unroll
      for (int r = 0; r < 4; ++r){
        int c = 16*m + 4*g4 + r;
        float s = trS[c], bb2 = trB[c];
        acc[m][0][r] = lrelu(s*acc[m][0][r] + bb2) + pacc[m][0][r];
        acc[m][1][r] = lrelu(s*acc[m][1][r] + bb2) + pacc[m][1][r];
      }
    }

    // (8) hidden epilogues -> gab (gate_h ch 0..15, attn_h ch 16..31)
    {
      int hc = 4*g4;
      float gs0 = gaS[hc+0], gs1 = gaS[hc+1], gs2 = gaS[hc+2], gs3 = gaS[hc+3];
      float gc0 = gaB[hc+0], gc1 = gaB[hc+1], gc2 = gaB[hc+2], gc3 = gaB[hc+3];
      float as0 = atS[hc+0], as1 = atS[hc+1], as2 = atS[hc+2], as3 = atS[hc+3];
      float ac0 = atB[hc+0], ac1 = atB[hc+1], ac2 = atB[hc+2], ac3 = atB[hc+3];
      #pragma unroll
      for (int ct = 0; ct < 2; ++ct){
        int lc = (ct == 0) ? lc0 : lc1;
        float q0 = lrelu(gs0*acc[4][ct][0] + gc0), q1 = lrelu(gs1*acc[4][ct][1] + gc1);
        float q2 = lrelu(gs2*acc[4][ct][2] + gc2), q3 = lrelu(gs3*acc[4][ct][3] + gc3);
        *(uint2*)(gab + lc*40 + hc) = make_uint2(pk2(q0,q1), pk2(q2,q3));
        float a0 = lrelu(as0*acc[5][ct][0] + ac0), a1 = lrelu(as1*acc[5][ct][1] + ac1);
        float a2 = lrelu(as2*acc[5][ct][2] + ac2), a3 = lrelu(as3*acc[5][ct][3] + ac3);
        *(uint2*)(gab + lc*40 + 16 + hc) = make_uint2(pk2(a0,a1), pk2(a2,a3));
      }
    }
    // pos_enc -> posb (bf16) for pe_proj (overwrites dead h1)
    #pragma unroll
    for (int m2 = 0; m2 < 4; ++m2){
      int cb2 = 16*m2 + 4*g4;
      *(uint2*)(posb + lc0*72 + cb2) =
        make_uint2(pk2(pacc[m2][0][0],pacc[m2][0][1]), pk2(pacc[m2][0][2],pacc[m2][0][3]));
      *(uint2*)(posb + lc1*72 + cb2) =
        make_uint2(pk2(pacc[m2][1][0],pacc[m2][1][1]), pk2(pacc[m2][1][2],pacc[m2][1][3]));
    }

    // (9) pe_proj + gate/attn layer-2 MFMAs
    f32x4 peac0 = {0.f,0.f,0.f,0.f}, peac1 = peac0, gac0 = peac0, gac1 = peac0;
    #pragma unroll
    for (int ks = 0; ks < 2; ++ks){
      bf16x8 p0 = *(const bf16x8*)(posb + lc0*72 + 32*ks + 8*g4);
      bf16x8 p1 = *(const bf16x8*)(posb + lc1*72 + 32*ks + 8*g4);
      peac0 = MFMA16(pef[ks], p0, peac0);
      peac1 = MFMA16(pef[ks], p1, peac1);
    }
    {
      bf16x8 g0 = *(const bf16x8*)(gab + lc0*40 + 8*g4);
      bf16x8 g1 = *(const bf16x8*)(gab + lc1*40 + 8*g4);
      gac0 = MFMA16(gaf, g0, gac0);
      gac1 = MFMA16(gaf, g1, gac1);
    }

    // (10) gate, logits, softmax over k, reductions, outacc
    float gv0 = __shfl(gac0[0], 32 + l15, 64);
    float gv1 = __shfl(gac1[0], 32 + l15, 64);
    float gb2v = gate_b2[0];
    float gm0 = 1.f/(1.f + __expf(-(gv0 + gb2v)));
    float gm1 = 1.f/(1.f + __expf(-(gv1 + gb2v)));
    float lg0 = __logf(gm0 + 1e-6f), lg1 = __logf(gm1 + 1e-6f);

    float wg0[4], wg1[4];
    #pragma unroll
    for (int r = 0; r < 4; ++r){
      int row = 4*g4 + r;
      float ab = (row < 8) ? attn_b2[row] : 0.f;
      float pb = (row < 8) ? pe_b[row] : 0.f;
      float t0 = gac0[r] + peac0[r] + ab + pb + lg0;
      float t1 = gac1[r] + peac1[r] + ab + pb + lg1;
      float mx = fmaxf(t0, t1);
      #pragma unroll
      for (int d = 1; d < 16; d <<= 1) mx = fmaxf(mx, __shfl_xor(mx, d, 64));
      float e0 = __expf(t0 - mx), e1 = __expf(t1 - mx);
      float s = e0 + e1;
      #pragma unroll
      for (int d = 1; d < 16; d <<= 1) s += __shfl_xor(s, d, 64);
      float inv = 1.f / s;
      wg0[r] = e0 * inv; wg1[r] = e1 * inv;
    }
    float wf0[8], wf1[8];
    #pragma unroll
    for (int gg = 0; gg < 8; ++gg){
      int src = 16*(gg >> 2) + l15;
      wf0[gg] = __shfl(wg0[gg & 3], src, 64);
      wf1[gg] = __shfl(wg1[gg & 3], src, 64);
    }
    const bool hi = (g4 >= 2);
    #pragma unroll
    for (int m = 0; m < 4; ++m){
      float w0 = hi ? wf0[2*m+1] : wf0[2*m];
      float w1 = hi ? wf1[2*m+1] : wf1[2*m];
      #pragma unroll
      for (int r = 0; r < 4; ++r){
        float sA = acc[m][0][r]*w0 + acc[m][1][r]*w1;
        float sM = fmaxf(acc[m][0][r]*gm0, acc[m][1][r]*gm1);
        #pragma unroll
        for (int d = 1; d < 16; d <<= 1){
          sA += __shfl_xor(sA, d, 64);
          sM = fmaxf(sM, __shfl_xor(sM, d, 64));
        }
        if (l15 == 0) outacc[(16*m + 4*g4 + r)*32 + 4*it + wv] = sA + sM;
      }
    }
  }

  __syncthreads();   // all waves' outacc visible
  #pragma unroll
  for (int t2 = 0; t2 < 2; ++t2){
    int idx = tid + 256*t2;            // 0..511 -> 512 float4
    int ch = idx >> 3, nq = idx & 7;
    f32x4 v = *(const f32x4*)(outacc + ch*32 + nq*4);
    *(f32x4*)(out + (((long)(b*64 + ch)) << 11) + nblk + nq*4) = v;
  }
}

extern "C" void kernel_launch(void* const* d_in, const int* in_sizes, int n_in,
                              void* d_out, int out_size, void* d_ws, size_t ws_size,
                              hipStream_t stream){
  (void)in_sizes; (void)n_in; (void)out_size; (void)d_ws; (void)ws_size;
  gsl_fused<<<dim3(512), dim3(256), 0, stream>>>(
    (const float*)d_in[0],  (const float*)d_in[1],  (const float*)d_in[2],
    (const float*)d_in[3],  (const float*)d_in[4],  (const float*)d_in[5],
    (const float*)d_in[6],  (const float*)d_in[7],  (const float*)d_in[8],
    (const float*)d_in[9],  (const float*)d_in[10], (const float*)d_in[11],
    (const float*)d_in[12], (const float*)d_in[13], (const float*)d_in[14],
    (const float*)d_in[15], (const float*)d_in[16], (const float*)d_in[17],
    (const float*)d_in[18], (const float*)d_in[19], (const float*)d_in[20],
    (const float*)d_in[21], (const float*)d_in[22], (const float*)d_in[23],
    (const float*)d_in[24], (const float*)d_in[25], (const float*)d_in[26],
    (const float*)d_in[27], (const float*)d_in[28], (const float*)d_in[29],
    (float*)d_out);
}

// Round 4
// 116.059 us; speedup vs baseline: 1.7471x; 1.2551x over previous
//
#include <hip/hip_runtime.h>

// Grouped_Soft_GSL_Block_PE fused kernel for MI355X (gfx950).
// B=8, IC2=128, N=2048, K=32, C=64, G=8, CPG=8, hidden=16.
// R4: 512 blocks (2/CU), 256 thr / 4 waves; block owns 32 n, 8 iterations of
// (4 n)-tiles; wave wv owns n = nblk + 4*it + wv. Zero barriers in loop.
// Changes vs R3: named split prefetch (no spill), pe_proj folded into pos2
// (peW2 = pe_w@pos_w2 appended as wpos2 rows 64-71), DPP row_ror reductions
// instead of ds-shuffle butterflies, paired BN tables (ds_read_b64),
// scalar consts hoisted to registers.

typedef __attribute__((ext_vector_type(8))) short bf16x8;
typedef __attribute__((ext_vector_type(4))) float f32x4;

#define EPS_BN 1e-5f

__device__ __forceinline__ unsigned pk2(float a, float b){
  unsigned ua = __float_as_uint(a) + 0x8000u;
  unsigned ub = __float_as_uint(b) + 0x8000u;
  return __builtin_amdgcn_perm(ub, ua, 0x07060302);
}
__device__ __forceinline__ short f2bf(float a){
  unsigned u = __float_as_uint(a);
  u += 0x7FFFu + ((u >> 16) & 1u);
  return (short)(u >> 16);
}
__device__ __forceinline__ bf16x8 mk8(float4 a, float4 b){
  union { bf16x8 v; unsigned u[4]; } t;
  t.u[0] = pk2(a.x, a.y); t.u[1] = pk2(a.z, a.w);
  t.u[2] = pk2(b.x, b.y); t.u[3] = pk2(b.z, b.w);
  return t.v;
}
__device__ __forceinline__ float lrelu(float v){ return fmaxf(v, 0.2f*v); }

// DPP row_ror reductions over the 16-lane row (l15 = k dimension)
template<int N>
__device__ __forceinline__ float ror16(float x){
  return __int_as_float(__builtin_amdgcn_mov_dpp(__float_as_int(x), 0x120+N, 0xF, 0xF, false));
}
__device__ __forceinline__ float rsum16(float v){
  v += ror16<1>(v); v += ror16<2>(v); v += ror16<4>(v); v += ror16<8>(v); return v;
}
__device__ __forceinline__ float rmax16(float v){
  v = fmaxf(v, ror16<1>(v)); v = fmaxf(v, ror16<2>(v));
  v = fmaxf(v, ror16<4>(v)); v = fmaxf(v, ror16<8>(v)); return v;
}

#define MFMA16(a,b,c) __builtin_amdgcn_mfma_f32_16x16x32_bf16((a),(b),(c),0,0,0)

__global__ __launch_bounds__(256, 1)
void gsl_fused(const float* __restrict__ x,       const float* __restrict__ rel_pos,
               const float* __restrict__ pos_w1,  const float* __restrict__ pos_g,
               const float* __restrict__ pos_bb,  const float* __restrict__ pos_m,
               const float* __restrict__ pos_v,   const float* __restrict__ pos_w2,
               const float* __restrict__ pos_b2,  const float* __restrict__ pe_w,
               const float* __restrict__ pe_b,    const float* __restrict__ trans_w,
               const float* __restrict__ tr_g,    const float* __restrict__ tr_bb,
               const float* __restrict__ tr_m,    const float* __restrict__ tr_v,
               const float* __restrict__ gate_w1, const float* __restrict__ ga_g,
               const float* __restrict__ ga_bb,   const float* __restrict__ ga_m,
               const float* __restrict__ ga_v,    const float* __restrict__ gate_w2,
               const float* __restrict__ gate_b2, const float* __restrict__ attn_w1,
               const float* __restrict__ at_g,    const float* __restrict__ at_bb,
               const float* __restrict__ at_m,    const float* __restrict__ at_v,
               const float* __restrict__ attn_w2, const float* __restrict__ attn_b2,
               float* __restrict__ out)
{
  // LDS map (80832 B, 2 blocks/CU):
  // [0,34816)      xbuf [128 cols][136] bf16; wave slice 8704B at wv*8704,
  //                aliased post-GEMM per wave: h1b [32][72] @0, gab [32][40] @4608
  // [34816,60928)  wmain [96][136] bf16 (trans 0..63, gate 64..79, attn 80..95)
  // [60928,71296)  wpos2 [72][72] bf16 (rows 0..63 pos_w2; 64..71 peW2 fold;
  //                A-frag reads of rows 72..79 run into outacc -> junk rows,
  //                confined to unconsumed C rows)
  // [71296,79488)  outacc [64 ch][32 n] f32
  // [79488,80832)  tabs f32: trT[128] p1T[128] gaT[32] atT[32] peB[16]
  __shared__ __align__(16) char smem[80832];
  short* xbuf  = (short*)smem;
  short* wmain = (short*)(smem + 34816);
  short* wpos2 = (short*)(smem + 60928);
  float* outacc= (float*)(smem + 71296);
  float* tabs  = (float*)(smem + 79488);
  float* trT = tabs;          // (scale,bias) pairs, trans BN
  float* p1T = tabs + 128;    // pos1 BN
  float* gaT = tabs + 256;    // gate BN
  float* atT = tabs + 288;    // attn BN
  float* peBt= tabs + 320;    // pe_w@pos_b2 + pe_b (rows 8..15 zero)

  const int tid = threadIdx.x;
  const int wv  = tid >> 6;
  const int l   = tid & 63;
  const int l15 = l & 15, g4 = l >> 4;
  const int bid = blockIdx.x;
  const int b    = bid >> 6;
  const int nblk = (bid & 63) << 5;

  // ---- stage weights -> LDS bf16 ----
  if (tid < 192){
    int r = tid >> 1, c0 = (tid & 1) * 64;
    const float* src = (r < 64) ? (trans_w + r*128)
                     : (r < 80) ? (gate_w1 + (r-64)*128)
                                : (attn_w1 + (r-80)*128);
    src += c0;
    short* dst = wmain + r*136 + c0;
    #pragma unroll
    for (int j = 0; j < 8; ++j)
      *(bf16x8*)(dst + 8*j) = mk8(*(const float4*)(src + 8*j), *(const float4*)(src + 8*j + 4));
  } else {
    int r = tid - 192;
    const float* src = pos_w2 + r*64;
    short* dst = wpos2 + r*72;
    #pragma unroll
    for (int j = 0; j < 8; ++j)
      *(bf16x8*)(dst + 8*j) = mk8(*(const float4*)(src + 8*j), *(const float4*)(src + 8*j + 4));
  }
  // ---- BN fold tables (paired) + peB const ----
  if (tid < 64){
    float s = tr_g[tid] * rsqrtf(tr_v[tid] + EPS_BN);
    trT[2*tid] = s; trT[2*tid+1] = tr_bb[tid] - tr_m[tid]*s;
    float s2 = pos_g[tid] * rsqrtf(pos_v[tid] + EPS_BN);
    p1T[2*tid] = s2; p1T[2*tid+1] = pos_bb[tid] - pos_m[tid]*s2;
  } else if (tid < 80){
    int c = tid - 64;
    float s = ga_g[c] * rsqrtf(ga_v[c] + EPS_BN);
    gaT[2*c] = s; gaT[2*c+1] = ga_bb[c] - ga_m[c]*s;
  } else if (tid < 96){
    int c = tid - 80;
    float s = at_g[c] * rsqrtf(at_v[c] + EPS_BN);
    atT[2*c] = s; atT[2*c+1] = at_bb[c] - at_m[c]*s;
  } else if (tid < 112){
    int r2 = tid - 96;
    float v = 0.f;
    if (r2 < 8){
      v = pe_b[r2];
      for (int c = 0; c < 64; ++c) v += pe_w[r2*64 + c] * pos_b2[c];
    }
    peBt[r2] = v;
  }
  // ---- peW2 fold: rows 64..71 of wpos2 = pe_w @ pos_w2 ----
  {
    int o = 2*tid, r = o >> 6, j = o & 63;
    float c0 = 0.f, c1 = 0.f;
    for (int c = 0; c < 64; ++c){
      float a = pe_w[r*64 + c];
      c0 += a * pos_w2[c*64 + j];
      c1 += a * pos_w2[c*64 + j + 1];
    }
    *(unsigned*)(wpos2 + (64 + r)*72 + j) = pk2(c0, c1);
  }

  // ---- small weights / consts -> registers ----
  bf16x8 pw1f[4];
  #pragma unroll
  for (int m2 = 0; m2 < 4; ++m2){
    bf16x8 t = {0,0,0,0,0,0,0,0};
    if (g4 == 0){
      const float* rp = pos_w1 + (16*m2 + l15)*3;
      t[0] = f2bf(rp[0]); t[1] = f2bf(rp[1]); t[2] = f2bf(rp[2]);
    }
    pw1f[m2] = t;
  }
  bf16x8 gaf;
  {
    bf16x8 t = {0,0,0,0,0,0,0,0};
    #pragma unroll
    for (int j = 0; j < 8; ++j){
      int k = 8*g4 + j;
      float v2 = 0.f;
      if (l15 < 8)       { if (k >= 16) v2 = attn_w2[l15*16 + (k-16)]; }
      else if (l15 == 8) { if (k < 16)  v2 = gate_w2[k]; }
      t[j] = f2bf(v2);
    }
    gaf = t;
  }
  float pb2v[4][4];
  #pragma unroll
  for (int m2 = 0; m2 < 4; ++m2)
    #pragma unroll
    for (int r = 0; r < 4; ++r)
      pb2v[m2][r] = pos_b2[16*m2 + 4*g4 + r];
  const float gb2v = gate_b2[0];

  __syncthreads();   // LDS weights + tables visible

  float lcr[4];      // attn_b2 + peB combined logit const (needs peBt)
  #pragma unroll
  for (int r = 0; r < 4; ++r){
    int row = 4*g4 + r;
    lcr[r] = peBt[row] + ((row < 8) ? attn_b2[row] : 0.f);
  }

  // ---- per-wave constants ----
  const int col0 = 32*wv + l15, col1 = col0 + 16;
  const int lc0 = l15, lc1 = l15 + 16;
  const int lq = l & 7, ld = l >> 3;
  const int colb = 32*wv + 4*lq;
  char*  slice = smem + wv*8704;
  short* h1b   = (short*)slice;            // [32][72]
  short* gab   = (short*)(slice + 4608);   // [32][40]
  const float* xp0 = x + (((long)(b*128 + 8*ld)) << 16) + colb;
  const float* rpb = rel_pos + (((long)(3*b)) << 16);

  // ---- prologue: prefetch iteration 0 ----
  f32x4 fa[8], fb[8];
  float rc[6] = {0.f,0.f,0.f,0.f,0.f,0.f};
  {
    const long sb0 = (long)nblk * 32;
    #pragma unroll
    for (int j = 0; j < 8; ++j) fa[j] = *(const f32x4*)(xp0 + sb0 + (((long)j) << 16));
    #pragma unroll
    for (int j = 0; j < 8; ++j) fb[j] = *(const f32x4*)(xp0 + sb0 + (((long)(64+j)) << 16));
    if (g4 == 0){
      long sg = sb0 + col0;
      rc[0] = rpb[sg];          rc[1] = rpb[sg + 65536];      rc[2] = rpb[sg + 131072];
      rc[3] = rpb[sg + 16];     rc[4] = rpb[sg + 65536 + 16]; rc[5] = rpb[sg + 131072 + 16];
    }
  }

  for (int it = 0; it < 8; ++it){
    const long sbase = (long)nblk*32 + 128*it;

    // (1) cvt + write staged tile -> own xbuf slice (consumes fa,fb)
    #pragma unroll
    for (int i2 = 0; i2 < 4; ++i2){
      union { bf16x8 v; unsigned u[4]; } ta, tb2;
      ta.u[0] = pk2(fa[0][i2], fa[1][i2]); ta.u[1] = pk2(fa[2][i2], fa[3][i2]);
      ta.u[2] = pk2(fa[4][i2], fa[5][i2]); ta.u[3] = pk2(fa[6][i2], fa[7][i2]);
      *(bf16x8*)(xbuf + (colb+i2)*136 + 8*ld) = ta.v;
      tb2.u[0] = pk2(fb[0][i2], fb[1][i2]); tb2.u[1] = pk2(fb[2][i2], fb[3][i2]);
      tb2.u[2] = pk2(fb[4][i2], fb[5][i2]); tb2.u[3] = pk2(fb[6][i2], fb[7][i2]);
      *(bf16x8*)(xbuf + (colb+i2)*136 + 64 + 8*ld) = tb2.v;
    }
    float cr[6];
    #pragma unroll
    for (int q = 0; q < 6; ++q) cr[q] = rc[q];

    const long nsb = sbase + ((it < 7) ? 128 : 0);
    // (2) prefetch fa half for next iter (in flight across GEMM)
    #pragma unroll
    for (int j = 0; j < 8; ++j) fa[j] = *(const f32x4*)(xp0 + nsb + (((long)j) << 16));

    // (3) main GEMM: [96x128] @ xtile
    f32x4 acc[6][2];
    #pragma unroll
    for (int m = 0; m < 6; ++m){
      f32x4 z = {0.f,0.f,0.f,0.f};
      acc[m][0] = z; acc[m][1] = z;
    }
    #pragma unroll
    for (int ks = 0; ks < 4; ++ks){
      bf16x8 b0 = *(const bf16x8*)(xbuf + col0*136 + 32*ks + 8*g4);
      bf16x8 b1 = *(const bf16x8*)(xbuf + col1*136 + 32*ks + 8*g4);
      #pragma unroll
      for (int m = 0; m < 6; ++m){
        bf16x8 af = *(const bf16x8*)(wmain + (16*m + l15)*136 + 32*ks + 8*g4);
        acc[m][0] = MFMA16(af, b0, acc[m][0]);
        acc[m][1] = MFMA16(af, b1, acc[m][1]);
      }
    }

    // (4) prefetch fb half + rel for next iter (in flight across epilogue)
    #pragma unroll
    for (int j = 0; j < 8; ++j) fb[j] = *(const f32x4*)(xp0 + nsb + (((long)(64+j)) << 16));
    if (g4 == 0){
      long sg = nsb + col0;
      rc[0] = rpb[sg];          rc[1] = rpb[sg + 65536];      rc[2] = rpb[sg + 131072];
      rc[3] = rpb[sg + 16];     rc[4] = rpb[sg + 65536 + 16]; rc[5] = rpb[sg + 131072 + 16];
    }

    // (5) pos layer 1 (K padded 3->32) -> h1b
    {
      bf16x8 rf0 = {0,0,0,0,0,0,0,0}, rf1 = {0,0,0,0,0,0,0,0};
      if (g4 == 0){
        rf0[0] = f2bf(cr[0]); rf0[1] = f2bf(cr[1]); rf0[2] = f2bf(cr[2]);
        rf1[0] = f2bf(cr[3]); rf1[1] = f2bf(cr[4]); rf1[2] = f2bf(cr[5]);
      }
      #pragma unroll
      for (int m2 = 0; m2 < 4; ++m2){
        f32x4 z = {0.f,0.f,0.f,0.f};
        f32x4 d0 = MFMA16(pw1f[m2], rf0, z);
        f32x4 d1 = MFMA16(pw1f[m2], rf1, z);
        int cb2 = 16*m2 + 4*g4;
        float2 t0 = *(const float2*)(p1T + 2*(cb2+0));
        float2 t1 = *(const float2*)(p1T + 2*(cb2+1));
        float2 t2 = *(const float2*)(p1T + 2*(cb2+2));
        float2 t3 = *(const float2*)(p1T + 2*(cb2+3));
        float h0 = lrelu(t0.x*d0[0]+t0.y), h1v = lrelu(t1.x*d0[1]+t1.y);
        float h2 = lrelu(t2.x*d0[2]+t2.y), h3 = lrelu(t3.x*d0[3]+t3.y);
        *(uint2*)(h1b + lc0*72 + cb2) = make_uint2(pk2(h0,h1v), pk2(h2,h3));
        h0 = lrelu(t0.x*d1[0]+t0.y); h1v = lrelu(t1.x*d1[1]+t1.y);
        h2 = lrelu(t2.x*d1[2]+t2.y); h3 = lrelu(t3.x*d1[3]+t3.y);
        *(uint2*)(h1b + lc1*72 + cb2) = make_uint2(pk2(h0,h1v), pk2(h2,h3));
      }
    }

    // (6) pos2 + pe-fold: rows 0..63 pos_enc, 64..71 pe logits
    f32x4 pacc[5][2];
    #pragma unroll
    for (int m2 = 0; m2 < 5; ++m2){
      f32x4 z = {0.f,0.f,0.f,0.f};
      pacc[m2][0] = z; pacc[m2][1] = z;
    }
    #pragma unroll
    for (int ks = 0; ks < 2; ++ks){
      bf16x8 h0 = *(const bf16x8*)(h1b + lc0*72 + 32*ks + 8*g4);
      bf16x8 h1v = *(const bf16x8*)(h1b + lc1*72 + 32*ks + 8*g4);
      #pragma unroll
      for (int m2 = 0; m2 < 5; ++m2){
        bf16x8 af = *(const bf16x8*)(wpos2 + (16*m2 + l15)*72 + 32*ks + 8*g4);
        pacc[m2][0] = MFMA16(af, h0, pacc[m2][0]);
        pacc[m2][1] = MFMA16(af, h1v, pacc[m2][1]);
      }
    }
    #pragma unroll
    for (int m2 = 0; m2 < 4; ++m2)
      #pragma unroll
      for (int r = 0; r < 4; ++r){
        pacc[m2][0][r] += pb2v[m2][r];
        pacc[m2][1][r] += pb2v[m2][r];
      }

    // (7) trans epilogue: trans_feat = lrelu(BN(conv)) + pos_enc
    #pragma unroll
    for (int m = 0; m < 4; ++m)
      #pragma unroll
      for (int r = 0; r < 4; ++r){
        float2 tb = *(const float2*)(trT + 2*(16*m + 4*g4 + r));
        acc[m][0][r] = lrelu(tb.x*acc[m][0][r] + tb.y) + pacc[m][0][r];
        acc[m][1][r] = lrelu(tb.x*acc[m][1][r] + tb.y) + pacc[m][1][r];
      }

    // (8) hidden epilogues -> gab (gate_h ch 0..15, attn_h ch 16..31)
    {
      int hc = 4*g4;
      float2 g0p = *(const float2*)(gaT + 2*(hc+0));
      float2 g1p = *(const float2*)(gaT + 2*(hc+1));
      float2 g2p = *(const float2*)(gaT + 2*(hc+2));
      float2 g3p = *(const float2*)(gaT + 2*(hc+3));
      float2 a0p = *(const float2*)(atT + 2*(hc+0));
      float2 a1p = *(const float2*)(atT + 2*(hc+1));
      float2 a2p = *(const float2*)(atT + 2*(hc+2));
      float2 a3p = *(const float2*)(atT + 2*(hc+3));
      #pragma unroll
      for (int ct = 0; ct < 2; ++ct){
        int lc = (ct == 0) ? lc0 : lc1;
        float q0 = lrelu(g0p.x*acc[4][ct][0] + g0p.y), q1 = lrelu(g1p.x*acc[4][ct][1] + g1p.y);
        float q2 = lrelu(g2p.x*acc[4][ct][2] + g2p.y), q3 = lrelu(g3p.x*acc[4][ct][3] + g3p.y);
        *(uint2*)(gab + lc*40 + hc) = make_uint2(pk2(q0,q1), pk2(q2,q3));
        float a0 = lrelu(a0p.x*acc[5][ct][0] + a0p.y), a1 = lrelu(a1p.x*acc[5][ct][1] + a1p.y);
        float a2 = lrelu(a2p.x*acc[5][ct][2] + a2p.y), a3 = lrelu(a3p.x*acc[5][ct][3] + a3p.y);
        *(uint2*)(gab + lc*40 + 16 + hc) = make_uint2(pk2(a0,a1), pk2(a2,a3));
      }
    }

    // (9) gate/attn layer-2 MFMA (rows 0..7 attn, row 8 gate)
    f32x4 gac0 = {0.f,0.f,0.f,0.f}, gac1 = gac0;
    {
      bf16x8 g0 = *(const bf16x8*)(gab + lc0*40 + 8*g4);
      bf16x8 g1 = *(const bf16x8*)(gab + lc1*40 + 8*g4);
      gac0 = MFMA16(gaf, g0, gac0);
      gac1 = MFMA16(gaf, g1, gac1);
    }

    // (10) gate, logits, softmax over k (DPP reduce), outputs
    float gv0 = __shfl(gac0[0], 32 + l15, 64);
    float gv1 = __shfl(gac1[0], 32 + l15, 64);
    float gm0 = 1.f/(1.f + __expf(-(gv0 + gb2v)));
    float gm1 = 1.f/(1.f + __expf(-(gv1 + gb2v)));
    float lg0 = __logf(gm0 + 1e-6f), lg1 = __logf(gm1 + 1e-6f);

    float wg0[4], wg1[4];
    #pragma unroll
    for (int r = 0; r < 4; ++r){
      float t0 = gac0[r] + pacc[4][0][r] + lcr[r] + lg0;
      float t1 = gac1[r] + pacc[4][1][r] + lcr[r] + lg1;
      float mx = rmax16(fmaxf(t0, t1));
      float e0 = __expf(t0 - mx), e1 = __expf(t1 - mx);
      float inv = 1.f / rsum16(e0 + e1);
      wg0[r] = e0 * inv; wg1[r] = e1 * inv;
    }
    float wf0[8], wf1[8];
    #pragma unroll
    for (int gg = 0; gg < 8; ++gg){
      int src = 16*(gg >> 2) + l15;
      wf0[gg] = __shfl(wg0[gg & 3], src, 64);
      wf1[gg] = __shfl(wg1[gg & 3], src, 64);
    }
    const bool hi = (g4 >= 2);
    #pragma unroll
    for (int m = 0; m < 4; ++m){
      float w0 = hi ? wf0[2*m+1] : wf0[2*m];
      float w1 = hi ? wf1[2*m+1] : wf1[2*m];
      #pragma unroll
      for (int r = 0; r < 4; ++r){
        float sA = rsum16(acc[m][0][r]*w0 + acc[m][1][r]*w1);
        float sM = rmax16(fmaxf(acc[m][0][r]*gm0, acc[m][1][r]*gm1));
        if (l15 == 0) outacc[(16*m + 4*g4 + r)*32 + 4*it + wv] = sA + sM;
      }
    }
  }

  __syncthreads();   // all waves' outacc visible
  #pragma unroll
  for (int t2 = 0; t2 < 2; ++t2){
    int idx = tid + 256*t2;            // 512 float4
    int ch = idx >> 3, nq = idx & 7;
    f32x4 v = *(const f32x4*)(outacc + ch*32 + nq*4);
    *(f32x4*)(out + (((long)(b*64 + ch)) << 11) + nblk + nq*4) = v;
  }
}

extern "C" void kernel_launch(void* const* d_in, const int* in_sizes, int n_in,
                              void* d_out, int out_size, void* d_ws, size_t ws_size,
                              hipStream_t stream){
  (void)in_sizes; (void)n_in; (void)out_size; (void)d_ws; (void)ws_size;
  gsl_fused<<<dim3(512), dim3(256), 0, stream>>>(
    (const float*)d_in[0],  (const float*)d_in[1],  (const float*)d_in[2],
    (const float*)d_in[3],  (const float*)d_in[4],  (const float*)d_in[5],
    (const float*)d_in[6],  (const float*)d_in[7],  (const float*)d_in[8],
    (const float*)d_in[9],  (const float*)d_in[10], (const float*)d_in[11],
    (const float*)d_in[12], (const float*)d_in[13], (const float*)d_in[14],
    (const float*)d_in[15], (const float*)d_in[16], (const float*)d_in[17],
    (const float*)d_in[18], (const float*)d_in[19], (const float*)d_in[20],
    (const float*)d_in[21], (const float*)d_in[22], (const float*)d_in[23],
    (const float*)d_in[24], (const float*)d_in[25], (const float*)d_in[26],
    (const float*)d_in[27], (const float*)d_in[28], (const float*)d_in[29],
    (float*)d_out);
}